// Round 1
// baseline (353.771 us; speedup 1.0000x reference)
//
#include <hip/hip_runtime.h>

// coif4 decomposition low-pass filter (24 taps). REC_LO[k]=DEC_LO[23-k], REC_HI[k]=(-1)^k*DEC_LO[k]
__device__ __constant__ float DEC_LO[24] = {
    -1.7849850030882614e-06f, -3.2596802368833675e-06f, 3.1229875865345646e-05f,
    6.233903446100713e-05f, -0.00025997455248771324f, -0.0005890207562443383f,
    0.0012665619292989445f, 0.003751436157278457f, -0.00565828668661072f,
    -0.015211731527946259f, 0.025082261844864097f, 0.03933442712333749f,
    -0.09622044203398798f, -0.06662747426342504f, 0.4343860564914685f,
    0.782238930920499f, 0.41530840703043026f, -0.05607731331675481f,
    -0.08126669968087875f, 0.026682300156053072f, 0.016068943964776348f,
    -0.0073461663276420935f, -0.0016294920126017326f, 0.0008923136685823146f
};

struct V6 {
    const float* ll[6];
    const float* yh[6];   // [C][3][h][w]
    float* lo[6];
    float* hi[6];
    int h[6], w[6];
    int boff[7];
};

// Vertical (row-axis) synthesis: lo/hi[c][2m+e][x] from ll/lh (band0) and hl/hh (bands 1,2)
__global__ __launch_bounds__(256) void idwt_v(V6 a) {
    int bid = blockIdx.x;
    int i = 0;
    while (i < 5 && bid >= a.boff[i + 1]) ++i;
    int h = a.h[i], w = a.w[i];
    unsigned t = (unsigned)(bid - a.boff[i]) * 256u + threadIdx.x;
    unsigned hw = (unsigned)(h * w);
    if (t >= 32u * hw) return;
    unsigned c = t / hw;
    unsigned rem = t - c * hw;
    unsigned m = rem / (unsigned)w;
    unsigned x = rem - m * (unsigned)w;

    const float* llc = a.ll[i] + (size_t)c * hw;
    const float* lhc = a.yh[i] + (size_t)(c * 3 + 0) * hw;
    const float* hlc = a.yh[i] + (size_t)(c * 3 + 1) * hw;
    const float* hhc = a.yh[i] + (size_t)(c * 3 + 2) * hw;

    float lo0 = 0.f, lo1 = 0.f, hi0 = 0.f, hi1 = 0.f;
#pragma unroll
    for (int j = 0; j < 12; ++j) {
        int r = (int)m - j; if (r < 0) r += h;
        unsigned idx = (unsigned)r * (unsigned)w + x;
        float vll = llc[idx], vlh = lhc[idx], vhl = hlc[idx], vhh = hhc[idx];
        float rl0 = DEC_LO[23 - 2 * j], rl1 = DEC_LO[22 - 2 * j];
        float rh0 = DEC_LO[2 * j],      rh1 = -DEC_LO[2 * j + 1];
        lo0 += rl0 * vll + rh0 * vlh;
        lo1 += rl1 * vll + rh1 * vlh;
        hi0 += rl0 * vhl + rh0 * vhh;
        hi1 += rl1 * vhl + rh1 * vhh;
    }
    size_t ob = ((size_t)c * 2 * h + 2 * m) * w + x;
    a.lo[i][ob] = lo0;
    a.lo[i][ob + w] = lo1;
    a.hi[i][ob] = hi0;
    a.hi[i][ob + w] = hi1;
}

struct H6 {
    const float* lo[6];
    const float* hi[6];
    float* out[6];
    int rows[6], w[6];
    int boff[7];
};

// Horizontal (col-axis) synthesis, channel-first output [C][rows][2w]
__global__ __launch_bounds__(256) void idwt_h(H6 a) {
    int bid = blockIdx.x;
    int i = 0;
    while (i < 5 && bid >= a.boff[i + 1]) ++i;
    int rows = a.rows[i], w = a.w[i];
    unsigned t = (unsigned)(bid - a.boff[i]) * 256u + threadIdx.x;
    unsigned rw = (unsigned)(rows * w);
    if (t >= 32u * rw) return;
    unsigned c = t / rw;
    unsigned rem = t - c * rw;
    unsigned y = rem / (unsigned)w;
    unsigned m = rem - y * (unsigned)w;

    const float* lop = a.lo[i] + ((size_t)c * rows + y) * w;
    const float* hpp = a.hi[i] + ((size_t)c * rows + y) * w;
    float o0 = 0.f, o1 = 0.f;
#pragma unroll
    for (int j = 0; j < 12; ++j) {
        int r = (int)m - j; if (r < 0) r += w;
        float vl = lop[r], vh = hpp[r];
        o0 += DEC_LO[23 - 2 * j] * vl + DEC_LO[2 * j] * vh;
        o1 += DEC_LO[22 - 2 * j] * vl - DEC_LO[2 * j + 1] * vh;
    }
    float2* op = (float2*)(a.out[i] + (((size_t)c * rows + y) * 2 * w + 2 * m));
    *op = make_float2(o0, o1);
}

struct HT6 {
    const float* lo[6];
    const float* hi[6];
    float* out[6];  // channel-last [256][2*w2][32]
    int w2[6];
    int boff[7];
};

// Final horizontal synthesis + transpose to channel-last. One block per output row y (256 rows/plane).
__global__ __launch_bounds__(256) void idwt_ht(HT6 a) {
    __shared__ float lo_s[32 * 129];
    __shared__ float hi_s[32 * 129];
    int bid = blockIdx.x;
    int i = 0;
    while (i < 5 && bid >= a.boff[i + 1]) ++i;
    int w2 = a.w2[i];
    int y = bid - a.boff[i];
    int stride = w2 + 1;  // pad -> conflict-free column reads across channels
    int tid = threadIdx.x;

    for (int idx = tid; idx < 32 * w2; idx += 256) {
        int c = idx / w2, x = idx - c * w2;
        size_t g = ((size_t)c * 256 + y) * w2 + x;
        lo_s[c * stride + x] = a.lo[i][g];
        hi_s[c * stride + x] = a.hi[i][g];
    }
    __syncthreads();

    int W = 2 * w2;
    float* orow = a.out[i] + (size_t)y * W * 32;
    for (int idx = tid; idx < 32 * w2; idx += 256) {
        int m = idx >> 5, c = idx & 31;
        float o0 = 0.f, o1 = 0.f;
#pragma unroll
        for (int j = 0; j < 12; ++j) {
            int r = m - j; if (r < 0) r += w2;
            float vl = lo_s[c * stride + r], vh = hi_s[c * stride + r];
            o0 += DEC_LO[23 - 2 * j] * vl + DEC_LO[2 * j] * vh;
            o1 += DEC_LO[22 - 2 * j] * vl - DEC_LO[2 * j + 1] * vh;
        }
        orow[(2 * m) * 32 + c] = o0;
        orow[(2 * m + 1) * 32 + c] = o1;
    }
}

struct S6 {
    const float* pl[6];  // channel-last planes [256][W][32]
};

__global__ __launch_bounds__(256) void sample_k(const float* __restrict__ pts,
                                                const float* __restrict__ ts,
                                                S6 a, float* __restrict__ out, int Npts) {
    int g = blockIdx.x * 256 + threadIdx.x;
    int p = g >> 3;
    int qq = (g & 7) << 2;  // channel offset 0,4,...,28
    if (p >= Npts) return;

    const float sc = (float)(2.0 / (-2.0 * 1.3));
    float p4[4];
    p4[0] = (pts[p * 3 + 0] - 1.3f) * sc - 1.0f;
    p4[1] = (pts[p * 3 + 1] - 1.3f) * sc - 1.0f;
    p4[2] = (pts[p * 3 + 2] - 1.3f) * sc - 1.0f;
    p4[3] = ts[p] * 2.0f - 1.0f;

    const int PW[6] = {256, 256, 64, 256, 64, 64};
    const int QI[6] = {0, 0, 3, 1, 3, 3};
    const int RI[6] = {1, 2, 0, 2, 1, 2};

    float4 acc = make_float4(1.f, 1.f, 1.f, 1.f);
#pragma unroll
    for (int i = 0; i < 6; ++i) {
        int W = PW[i];
        float cx = p4[QI[i]];
        float cy = p4[RI[i]];
        float fx = (cx + 1.0f) * 0.5f * (float)(W - 1);
        fx = fminf(fmaxf(fx, 0.0f), (float)(W - 1));
        float fy = (cy + 1.0f) * 0.5f * 255.0f;
        fy = fminf(fmaxf(fy, 0.0f), 255.0f);
        float x0 = fminf(fmaxf(floorf(fx), 0.0f), (float)(W - 2));
        float y0 = fminf(fmaxf(floorf(fy), 0.0f), 254.0f);
        float wx = fx - x0, wy = fy - y0;
        int xi = (int)x0, yi = (int)y0;

        const float* base = a.pl[i] + ((size_t)yi * W + xi) * 32 + qq;
        float4 v00 = *(const float4*)(base);
        float4 v01 = *(const float4*)(base + 32);
        float4 v10 = *(const float4*)(base + (size_t)W * 32);
        float4 v11 = *(const float4*)(base + (size_t)W * 32 + 32);

        float w00 = (1.f - wy) * (1.f - wx), w01 = (1.f - wy) * wx;
        float w10 = wy * (1.f - wx), w11 = wy * wx;
        float4 f;
        f.x = v00.x * w00 + v01.x * w01 + v10.x * w10 + v11.x * w11;
        f.y = v00.y * w00 + v01.y * w01 + v10.y * w10 + v11.y * w11;
        f.z = v00.z * w00 + v01.z * w01 + v10.z * w10 + v11.z * w11;
        f.w = v00.w * w00 + v01.w * w01 + v10.w * w10 + v11.w * w11;
        acc.x *= f.x; acc.y *= f.y; acc.z *= f.z; acc.w *= f.w;
    }
    *(float4*)(out + (size_t)p * 32 + qq) = acc;
}

extern "C" void kernel_launch(void* const* d_in, const int* in_sizes, int n_in,
                              void* d_out, int out_size, void* d_ws, size_t ws_size,
                              hipStream_t stream) {
    const float* pts = (const float*)d_in[0];
    const float* ts = (const float*)d_in[1];
    const int PWt[6] = {256, 256, 64, 256, 64, 64};
    const int Npts = in_sizes[0] / 3;

    float* ws = (float*)d_ws;
    float *planeT[6], *x1[6], *lo2[6], *hi2[6], *lo1[6], *hi1[6];
    size_t off = 0;
    for (int i = 0; i < 6; ++i) {
        int W = PWt[i], H = 256;
        int w2 = W / 2, h2 = 128, w4 = W / 4;
        planeT[i] = ws + off;            // [H][W][32]; x1 aliases front (dead before planeT written)
        x1[i] = planeT[i];               // [32][h2][w2]
        off += (size_t)H * W * 32;
        lo2[i] = ws + off;               // [32][H][w2]; lo1/hi1 alias front (dead before lo2 written)
        hi2[i] = lo2[i] + (size_t)H * w2 * 32;
        lo1[i] = lo2[i];                 // [32][h2][w4]
        hi1[i] = lo1[i] + (size_t)h2 * w4 * 32;
        off += 2 * (size_t)H * w2 * 32;
    }

    // ---- Level 1 vertical: yl (ll) + yhb bands -> lo1, hi1
    V6 v1;
    int b = 0;
    for (int i = 0; i < 6; ++i) {
        int w4 = PWt[i] / 4;
        v1.ll[i] = (const float*)d_in[2 + 3 * i];       // yl
        v1.yh[i] = (const float*)d_in[4 + 3 * i];       // yhb
        v1.lo[i] = lo1[i];
        v1.hi[i] = hi1[i];
        v1.h[i] = 64; v1.w[i] = w4;
        v1.boff[i] = b;
        b += (32 * 64 * w4 + 255) / 256;
    }
    v1.boff[6] = b;
    idwt_v<<<b, 256, 0, stream>>>(v1);

    // ---- Level 1 horizontal: lo1/hi1 -> x1 [32][128][w2]
    H6 h1;
    b = 0;
    for (int i = 0; i < 6; ++i) {
        int w4 = PWt[i] / 4;
        h1.lo[i] = lo1[i]; h1.hi[i] = hi1[i]; h1.out[i] = x1[i];
        h1.rows[i] = 128; h1.w[i] = w4;
        h1.boff[i] = b;
        b += (32 * 128 * w4 + 255) / 256;
    }
    h1.boff[6] = b;
    idwt_h<<<b, 256, 0, stream>>>(h1);

    // ---- Level 2 vertical: x1 (ll) + yha bands -> lo2, hi2 [32][256][w2]
    V6 v2;
    b = 0;
    for (int i = 0; i < 6; ++i) {
        int w2 = PWt[i] / 2;
        v2.ll[i] = x1[i];
        v2.yh[i] = (const float*)d_in[3 + 3 * i];       // yha
        v2.lo[i] = lo2[i];
        v2.hi[i] = hi2[i];
        v2.h[i] = 128; v2.w[i] = w2;
        v2.boff[i] = b;
        b += (32 * 128 * w2 + 255) / 256;
    }
    v2.boff[6] = b;
    idwt_v<<<b, 256, 0, stream>>>(v2);

    // ---- Level 2 horizontal + transpose -> planeT [256][W][32]
    HT6 ht;
    b = 0;
    for (int i = 0; i < 6; ++i) {
        ht.lo[i] = lo2[i]; ht.hi[i] = hi2[i]; ht.out[i] = planeT[i];
        ht.w2[i] = PWt[i] / 2;
        ht.boff[i] = b;
        b += 256;
    }
    ht.boff[6] = b;
    idwt_ht<<<b, 256, 0, stream>>>(ht);

    // ---- Sampling: 8 lanes per point, 4 channels per lane
    S6 s;
    for (int i = 0; i < 6; ++i) s.pl[i] = planeT[i];
    int total = Npts * 8;
    int blocks = (total + 255) / 256;
    sample_k<<<blocks, 256, 0, stream>>>(pts, ts, s, (float*)d_out, Npts);
}

// Round 2
// 288.293 us; speedup vs baseline: 1.2271x; 1.2271x over previous
//
#include <hip/hip_runtime.h>
#include <hip/hip_fp16.h>

// coif4 decomposition low-pass filter (24 taps). REC_LO[k]=DEC_LO[23-k], REC_HI[k]=(-1)^k*DEC_LO[k]
__device__ __constant__ float DEC_LO[24] = {
    -1.7849850030882614e-06f, -3.2596802368833675e-06f, 3.1229875865345646e-05f,
    6.233903446100713e-05f, -0.00025997455248771324f, -0.0005890207562443383f,
    0.0012665619292989445f, 0.003751436157278457f, -0.00565828668661072f,
    -0.015211731527946259f, 0.025082261844864097f, 0.03933442712333749f,
    -0.09622044203398798f, -0.06662747426342504f, 0.4343860564914685f,
    0.782238930920499f, 0.41530840703043026f, -0.05607731331675481f,
    -0.08126669968087875f, 0.026682300156053072f, 0.016068943964776348f,
    -0.0073461663276420935f, -0.0016294920126017326f, 0.0008923136685823146f
};

// ---------------- Level 1 fused (vertical + horizontal), one block per (plane, channel) --------
struct L1P {
    const float* yl[6];
    const float* yhb[6];  // [C][3][64][w4]
    float* x1[6];         // [C][128][w2] fp32
    int w4[6], lw4[6];
};

__global__ __launch_bounds__(256) void idwt_l1(L1P a) {
    __shared__ float s_lo[128 * 64];  // 32 KB (max: big plane w4=64)
    __shared__ float s_hi[128 * 64];  // 32 KB
    int i = blockIdx.x >> 5;
    int c = blockIdx.x & 31;
    int w4 = a.w4[i], lw4 = a.lw4[i];
    int tid = threadIdx.x;

    const float* llc = a.yl[i] + (size_t)c * 64 * w4;
    const float* lhc = a.yhb[i] + (size_t)(c * 3 + 0) * 64 * w4;
    const float* hlc = a.yhb[i] + (size_t)(c * 3 + 1) * 64 * w4;
    const float* hhc = a.yhb[i] + (size_t)(c * 3 + 2) * 64 * w4;

    // vertical pass: [64][w4] -> lo1/hi1 [128][w4] in LDS
    for (int idx = tid; idx < (64 << lw4); idx += 256) {
        int m = idx >> lw4, x = idx & (w4 - 1);
        float lo0 = 0.f, lo1 = 0.f, hi0 = 0.f, hi1 = 0.f;
#pragma unroll
        for (int j = 0; j < 12; ++j) {
            int r = (m - j) & 63;
            int ii = (r << lw4) + x;
            float vll = llc[ii], vlh = lhc[ii], vhl = hlc[ii], vhh = hhc[ii];
            float rl0 = DEC_LO[23 - 2 * j], rl1 = DEC_LO[22 - 2 * j];
            float rh0 = DEC_LO[2 * j],      rh1 = -DEC_LO[2 * j + 1];
            lo0 += rl0 * vll + rh0 * vlh;
            lo1 += rl1 * vll + rh1 * vlh;
            hi0 += rl0 * vhl + rh0 * vhh;
            hi1 += rl1 * vhl + rh1 * vhh;
        }
        s_lo[((2 * m) << lw4) + x] = lo0;
        s_lo[((2 * m + 1) << lw4) + x] = lo1;
        s_hi[((2 * m) << lw4) + x] = hi0;
        s_hi[((2 * m + 1) << lw4) + x] = hi1;
    }
    __syncthreads();

    // horizontal pass: -> x1 [128][w2] global fp32
    int w2 = w4 * 2;
    float* x1p = a.x1[i] + (size_t)c * 128 * w2;
    for (int idx = tid; idx < (128 << lw4); idx += 256) {
        int y = idx >> lw4, m = idx & (w4 - 1);
        float o0 = 0.f, o1 = 0.f;
#pragma unroll
        for (int j = 0; j < 12; ++j) {
            int r = (m - j) & (w4 - 1);
            float vl = s_lo[(y << lw4) + r], vh = s_hi[(y << lw4) + r];
            o0 += DEC_LO[23 - 2 * j] * vl + DEC_LO[2 * j] * vh;
            o1 += DEC_LO[22 - 2 * j] * vl - DEC_LO[2 * j + 1] * vh;
        }
        *(float2*)(x1p + (size_t)y * w2 + 2 * m) = make_float2(o0, o1);
    }
}

// ---------------- Level 2 vertical: x1 + yha -> lo2/hi2 fp16 [C][256][w2] --------
struct V2P {
    const float* x1[6];
    const float* yha[6];  // [C][3][128][w2]
    __half* lo2[6];
    __half* hi2[6];
    int w2[6], lw2[6];
    int boff[7];
};

__global__ __launch_bounds__(256) void idwt_v2(V2P a) {
    int bid = blockIdx.x;
    int i = 0;
    while (i < 5 && bid >= a.boff[i + 1]) ++i;
    int w2 = a.w2[i], lw2 = a.lw2[i];
    unsigned t = (unsigned)(bid - a.boff[i]) * 256u + threadIdx.x;
    unsigned hw = 128u << lw2;
    if (t >= (hw << 5)) return;
    unsigned c = t >> (7 + lw2);
    unsigned rem = t & (hw - 1);
    unsigned m = rem >> lw2;
    unsigned x = rem & (unsigned)(w2 - 1);

    const float* llc = a.x1[i] + (size_t)c * hw;
    const float* lhc = a.yha[i] + (size_t)(c * 3 + 0) * hw;
    const float* hlc = a.yha[i] + (size_t)(c * 3 + 1) * hw;
    const float* hhc = a.yha[i] + (size_t)(c * 3 + 2) * hw;

    float lo0 = 0.f, lo1 = 0.f, hi0 = 0.f, hi1 = 0.f;
#pragma unroll
    for (int j = 0; j < 12; ++j) {
        int r = ((int)m - j) & 127;
        unsigned idx = ((unsigned)r << lw2) + x;
        float vll = llc[idx], vlh = lhc[idx], vhl = hlc[idx], vhh = hhc[idx];
        float rl0 = DEC_LO[23 - 2 * j], rl1 = DEC_LO[22 - 2 * j];
        float rh0 = DEC_LO[2 * j],      rh1 = -DEC_LO[2 * j + 1];
        lo0 += rl0 * vll + rh0 * vlh;
        lo1 += rl1 * vll + rh1 * vlh;
        hi0 += rl0 * vhl + rh0 * vhh;
        hi1 += rl1 * vhl + rh1 * vhh;
    }
    size_t ob = ((size_t)c * 256 + 2 * m) * w2 + x;
    a.lo2[i][ob] = __float2half(lo0);
    a.lo2[i][ob + w2] = __float2half(lo1);
    a.hi2[i][ob] = __float2half(hi0);
    a.hi2[i][ob + w2] = __float2half(hi1);
}

// ---------------- Level 2 horizontal + transpose -> channel-last fp16 plane [256][W][32] --------
struct HTP {
    const __half* lo[6];
    const __half* hi[6];
    __half* out[6];
    int w2[6], lw2[6];
    int boff[7];
};

__global__ __launch_bounds__(256) void idwt_ht(HTP a) {
    __shared__ float lo_s[32 * 129];
    __shared__ float hi_s[32 * 129];
    int bid = blockIdx.x;
    int i = 0;
    while (i < 5 && bid >= a.boff[i + 1]) ++i;
    int w2 = a.w2[i], lw2 = a.lw2[i];
    int y = bid - a.boff[i];
    int stride = w2 + 1;
    int tid = threadIdx.x;

    for (int idx = tid; idx < (32 << lw2); idx += 256) {
        int c = idx >> lw2, x = idx & (w2 - 1);
        size_t g = ((size_t)c * 256 + y) * w2 + x;
        lo_s[c * stride + x] = __half2float(a.lo[i][g]);
        hi_s[c * stride + x] = __half2float(a.hi[i][g]);
    }
    __syncthreads();

    int W = 2 * w2;
    __half* orow = a.out[i] + (size_t)y * W * 32;
    for (int idx = tid; idx < (32 << lw2); idx += 256) {
        int m = idx >> 5, c = idx & 31;
        float o0 = 0.f, o1 = 0.f;
#pragma unroll
        for (int j = 0; j < 12; ++j) {
            int r = m - j; if (r < 0) r += w2;
            float vl = lo_s[c * stride + r], vh = hi_s[c * stride + r];
            o0 += DEC_LO[23 - 2 * j] * vl + DEC_LO[2 * j] * vh;
            o1 += DEC_LO[22 - 2 * j] * vl - DEC_LO[2 * j + 1] * vh;
        }
        orow[(2 * m) * 32 + c] = __float2half(o0);
        orow[(2 * m + 1) * 32 + c] = __float2half(o1);
    }
}

// ---------------- Sampling: 4 lanes/point, 8 channels/lane, fp16 planes --------
struct S6h {
    const __half* pl[6];  // [256][W][32] fp16
};

union H8 {
    float4 f4;
    __half h[8];
};

__global__ __launch_bounds__(256) void sample_k(const float* __restrict__ pts,
                                                const float* __restrict__ ts,
                                                S6h a, float* __restrict__ out, int Npts) {
    int g = blockIdx.x * 256 + threadIdx.x;
    int p = g >> 2;
    int ch8 = (g & 3) << 3;  // channel offset 0,8,16,24
    if (p >= Npts) return;

    const float sc = (float)(2.0 / (-2.0 * 1.3));
    float p4[4];
    p4[0] = (pts[p * 3 + 0] - 1.3f) * sc - 1.0f;
    p4[1] = (pts[p * 3 + 1] - 1.3f) * sc - 1.0f;
    p4[2] = (pts[p * 3 + 2] - 1.3f) * sc - 1.0f;
    p4[3] = ts[p] * 2.0f - 1.0f;

    const int PW[6] = {256, 256, 64, 256, 64, 64};
    const int QI[6] = {0, 0, 3, 1, 3, 3};
    const int RI[6] = {1, 2, 0, 2, 1, 2};

    float acc[8] = {1.f, 1.f, 1.f, 1.f, 1.f, 1.f, 1.f, 1.f};
#pragma unroll
    for (int i = 0; i < 6; ++i) {
        int W = PW[i];
        float cx = p4[QI[i]];
        float cy = p4[RI[i]];
        float fx = (cx + 1.0f) * 0.5f * (float)(W - 1);
        fx = fminf(fmaxf(fx, 0.0f), (float)(W - 1));
        float fy = (cy + 1.0f) * 0.5f * 255.0f;
        fy = fminf(fmaxf(fy, 0.0f), 255.0f);
        float x0 = fminf(fmaxf(floorf(fx), 0.0f), (float)(W - 2));
        float y0 = fminf(fmaxf(floorf(fy), 0.0f), 254.0f);
        float wx = fx - x0, wy = fy - y0;
        int xi = (int)x0, yi = (int)y0;

        const __half* base = a.pl[i] + ((size_t)yi * W + xi) * 32 + ch8;
        H8 u00, u01, u10, u11;
        u00.f4 = *(const float4*)(base);
        u01.f4 = *(const float4*)(base + 32);
        u10.f4 = *(const float4*)(base + (size_t)W * 32);
        u11.f4 = *(const float4*)(base + (size_t)W * 32 + 32);

        float w00 = (1.f - wy) * (1.f - wx), w01 = (1.f - wy) * wx;
        float w10 = wy * (1.f - wx), w11 = wy * wx;
#pragma unroll
        for (int k = 0; k < 8; ++k) {
            float f = w00 * __half2float(u00.h[k]) + w01 * __half2float(u01.h[k]) +
                      w10 * __half2float(u10.h[k]) + w11 * __half2float(u11.h[k]);
            acc[k] *= f;
        }
    }
    float* op = out + (size_t)p * 32 + ch8;
    *(float4*)(op) = make_float4(acc[0], acc[1], acc[2], acc[3]);
    *(float4*)(op + 4) = make_float4(acc[4], acc[5], acc[6], acc[7]);
}

extern "C" void kernel_launch(void* const* d_in, const int* in_sizes, int n_in,
                              void* d_out, int out_size, void* d_ws, size_t ws_size,
                              hipStream_t stream) {
    const float* pts = (const float*)d_in[0];
    const float* ts = (const float*)d_in[1];
    const int PWt[6] = {256, 256, 64, 256, 64, 64};
    const int Npts = in_sizes[0] / 3;

    char* ws = (char*)d_ws;
    float* x1[6];
    __half *lo2[6], *hi2[6], *planeH[6];
    size_t off = 0;
    for (int i = 0; i < 6; ++i) {
        int W = PWt[i], w2 = W / 2;
        x1[i] = (float*)(ws + off);      off += (size_t)32 * 128 * w2 * 4;
        lo2[i] = (__half*)(ws + off);    off += (size_t)32 * 256 * w2 * 2;
        hi2[i] = (__half*)(ws + off);    off += (size_t)32 * 256 * w2 * 2;
        planeH[i] = (__half*)(ws + off); off += (size_t)256 * W * 32 * 2;
    }

    // ---- Level 1 fused: yl + yhb -> x1 (fp32)
    L1P l1;
    for (int i = 0; i < 6; ++i) {
        int w4 = PWt[i] / 4;
        l1.yl[i] = (const float*)d_in[2 + 3 * i];
        l1.yhb[i] = (const float*)d_in[4 + 3 * i];
        l1.x1[i] = x1[i];
        l1.w4[i] = w4;
        l1.lw4[i] = (w4 == 64) ? 6 : 4;
    }
    idwt_l1<<<192, 256, 0, stream>>>(l1);

    // ---- Level 2 vertical: x1 + yha -> lo2/hi2 (fp16)
    V2P v2;
    int b = 0;
    for (int i = 0; i < 6; ++i) {
        int w2 = PWt[i] / 2;
        v2.x1[i] = x1[i];
        v2.yha[i] = (const float*)d_in[3 + 3 * i];
        v2.lo2[i] = lo2[i];
        v2.hi2[i] = hi2[i];
        v2.w2[i] = w2;
        v2.lw2[i] = (w2 == 128) ? 7 : 5;
        v2.boff[i] = b;
        b += (32 * 128 * w2) / 256;
    }
    v2.boff[6] = b;
    idwt_v2<<<b, 256, 0, stream>>>(v2);

    // ---- Level 2 horizontal + transpose -> channel-last fp16 planes
    HTP ht;
    b = 0;
    for (int i = 0; i < 6; ++i) {
        ht.lo[i] = lo2[i];
        ht.hi[i] = hi2[i];
        ht.out[i] = planeH[i];
        ht.w2[i] = PWt[i] / 2;
        ht.lw2[i] = (PWt[i] == 256) ? 7 : 5;
        ht.boff[i] = b;
        b += 256;
    }
    ht.boff[6] = b;
    idwt_ht<<<b, 256, 0, stream>>>(ht);

    // ---- Sampling: 4 lanes per point, 8 channels per lane
    S6h s;
    for (int i = 0; i < 6; ++i) s.pl[i] = planeH[i];
    int total = Npts * 4;
    int blocks = (total + 255) / 256;
    sample_k<<<blocks, 256, 0, stream>>>(pts, ts, s, (float*)d_out, Npts);
}